// Round 1
// baseline (27522.110 us; speedup 1.0000x reference)
//
#include <hip/hip_runtime.h>
#include <math.h>

#define S_LEN 4096
#define HID   2048
#define NBLK  256
#define NTHR  512   // 8 waves/block, 1 block/CU

typedef unsigned int       u32;
typedef unsigned long long u64;
typedef float v2f __attribute__((ext_vector_type(2)));

// R5: 4-byte tag-in-mantissa dataflow + wave-per-unit gate fusion.
//  - tagged entry = f32 hx value with its 2 mantissa LSBs replaced by tag
//    ((s+1)&3)^2 for step s. Within a parity buffer only tags {s, s-2} are
//    observable (producers can't run 2 steps ahead), and the tag cycle
//    {3,1}/{0,2} never aliases 0xAA poison (&3==2) before first overwrite.
//    4B atomic loads/stores halve the all-gather traffic vs R4's 8B entries.
//  - wave wv owns hidden unit m=8b+wv: its 4 columns are the 4 gates of m.
//    butterfly-reduce -> lanes 0..3 apply their own nonlinearity in parallel
//    (exp2-based sigmoid/tanh, no libcalls) -> 4 in-wave broadcasts -> lane 0
//    publishes. No second barrier, no gates_lds, no serialized 8-lane tail.
//  - speculative sweep: the 4-entry poll for step t+1 is issued right after
//    barrier A and checked after the publish, so it is in flight under the
//    entire FMA/reduce phase; the residual loop only chases stragglers.
//  - LDS overwrite safety without barrier B: a thread stages step-t data only
//    after seeing ALL 2048 tags, incl. its own block's 8 units, each published
//    program-order-after that wave's FMA reads of step t-1.

__device__ __forceinline__ float fast_sigmoid(float x) {
    float e = __builtin_amdgcn_exp2f(-1.44269504f * x);   // 2^(-x*log2e)
    return __builtin_amdgcn_rcpf(1.0f + e);
}

__global__ __launch_bounds__(NTHR, 2)
void qlstm_persistent(const float* __restrict__ inp,     // (S,1,4)
                      const float* __restrict__ conv_w,  // (4)
                      const float* __restrict__ conv_b,  // (1)
                      const float* __restrict__ Wg,      // (2049, 8192) row-major
                      const float* __restrict__ bg,      // (8192)
                      float* __restrict__ out,           // S*H + H + H
                      float* __restrict__ ws)            // scratch (poison 0xAA ok)
{
    const int b   = blockIdx.x;
    const int tid = threadIdx.x;
    const int l   = tid & 63;
    const int wv  = tid >> 6;

    u32* tb0 = (u32*)ws;            // [HID] tagged hx, parity 0 (holds even s)
    u32* tb1 = tb0 + HID + 32;      // [HID] tagged hx, parity 1 (holds odd s)

    __shared__ __align__(16) float hx_lds[HID];
    __shared__ __align__(16) float conv_lds[S_LEN];

    // ---------------- init phase ----------------
    {
        const float cw0 = conv_w[0], cw1 = conv_w[1], cw2 = conv_w[2], cw3 = conv_w[3];
        const float cb  = conv_b[0];
        for (int g = tid; g < S_LEN; g += NTHR) {
            float4 x = ((const float4*)inp)[g];
            float v = x.x*cw0 + x.y*cw1 + x.z*cw2 + x.w*cw3 + cb;
            conv_lds[g] = fast_sigmoid(v);
        }
    }
    // hx_0 = 0 lives purely in LDS: step 0 needs no global exchange at all.
    ((float4*)hx_lds)[tid] = make_float4(0.f, 0.f, 0.f, 0.f);

    const int m = b * 8 + wv;       // this wave's hidden unit

    // per-lane gate-column row-0 weight & bias (lanes 0..3 = gates f,i,g,o)
    float w0 = 0.f, bb = 0.f;
    if (l < 4) {
        int jc = (l << 11) + m;
        w0 = Wg[jc];
        bb = bg[jc];
    }

    // persistent W registers, packed for v_pk_fma_f32:
    //   wA[c][j] = rows 1+4l+256j+{0,1}, wB[c][j] = rows +{2,3}, col c*2048+m
    v2f wA[4][8], wB[4][8];
    #pragma unroll
    for (int j = 0; j < 8; ++j) {
        #pragma unroll
        for (int c = 0; c < 4; ++c) {
            const int jc = (c << 11) + m;
            const float* r0 = Wg + (size_t)(1 + 4*l + 256*j + 0) * 8192 + jc;
            const float* r1 = Wg + (size_t)(1 + 4*l + 256*j + 1) * 8192 + jc;
            const float* r2 = Wg + (size_t)(1 + 4*l + 256*j + 2) * 8192 + jc;
            const float* r3 = Wg + (size_t)(1 + 4*l + 256*j + 3) * 8192 + jc;
            v2f a; a.x = *r0; a.y = *r1;
            v2f bvec; bvec.x = *r2; bvec.y = *r3;
            wA[c][j] = a;
            wB[c][j] = bvec;
        }
    }

    float cx = 0.0f;                // replicated across all 64 lanes of wave wv
    const int e0 = tid * 4;         // this thread's 4 tagged entries
    u32 v0 = 0, v1 = 0, v2 = 0, v3 = 0;
    unsigned pend = 0;              // t=0 needs nothing (hx_0 zeros pre-staged)

    __syncthreads();

    // ---------------- recurrence ----------------
    for (int t = 0; t < S_LEN; ++t) {
        u32* tb = (t & 1) ? tb1 : tb0;     // hx_t lives here
        u32* tn = (t & 1) ? tb0 : tb1;     // hx_{t+1} goes here

        // ---- finish polling hx_t (spec sweep already cleared most of pend) ----
        const u32 want = (u32)(((t + 1) & 3) ^ 2);
        while (pend) {
            u32 a0 = 0, a1 = 0, a2 = 0, a3 = 0;
            if (pend & 1u) a0 = __hip_atomic_load(&tb[e0 + 0], __ATOMIC_RELAXED, __HIP_MEMORY_SCOPE_AGENT);
            if (pend & 2u) a1 = __hip_atomic_load(&tb[e0 + 1], __ATOMIC_RELAXED, __HIP_MEMORY_SCOPE_AGENT);
            if (pend & 4u) a2 = __hip_atomic_load(&tb[e0 + 2], __ATOMIC_RELAXED, __HIP_MEMORY_SCOPE_AGENT);
            if (pend & 8u) a3 = __hip_atomic_load(&tb[e0 + 3], __ATOMIC_RELAXED, __HIP_MEMORY_SCOPE_AGENT);
            if ((pend & 1u) && (a0 & 3u) == want) { v0 = a0; pend &= ~1u; }
            if ((pend & 2u) && (a1 & 3u) == want) { v1 = a1; pend &= ~2u; }
            if ((pend & 4u) && (a2 & 3u) == want) { v2 = a2; pend &= ~4u; }
            if ((pend & 8u) && (a3 & 3u) == want) { v3 = a3; pend &= ~8u; }
        }
        if (t) {   // t=0: hx_lds already holds zeros
            uint4 st;
            st.x = v0 & ~3u; st.y = v1 & ~3u; st.z = v2 & ~3u; st.w = v3 & ~3u;
            ((uint4*)hx_lds)[tid] = st;     // ds_write_b128, conflict-free
        }
        __syncthreads();                    // A: hx_t staged

        // ---- speculative sweep for hx_{t+1}: in flight across the FMA ----
        u64 qa = 0, qb = 0;
        if (t + 1 < S_LEN) {
            qa = __hip_atomic_load((const u64*)&tn[e0],     __ATOMIC_RELAXED, __HIP_MEMORY_SCOPE_AGENT);
            qb = __hip_atomic_load((const u64*)&tn[e0 + 2], __ATOMIC_RELAXED, __HIP_MEMORY_SCOPE_AGENT);
        }

        // ---- 2048-MAC dot for the 4 gates of unit m (packed f32 FMA) ----
        const v2f* hl2 = (const v2f*)hx_lds;
        v2f acc0, acc1, acc2, acc3;
        acc0 = 0.f; acc1 = 0.f; acc2 = 0.f; acc3 = 0.f;
        #pragma unroll
        for (int j = 0; j < 8; ++j) {
            v2f hA = hl2[2*(l + 64*j)];     // merged ds_read_b128
            v2f hB = hl2[2*(l + 64*j) + 1];
            acc0 += hA * wA[0][j];  acc0 += hB * wB[0][j];
            acc1 += hA * wA[1][j];  acc1 += hB * wB[1][j];
            acc2 += hA * wA[2][j];  acc2 += hB * wB[2][j];
            acc3 += hA * wA[3][j];  acc3 += hB * wB[3][j];
        }
        float s0 = acc0.x + acc0.y;
        float s1 = acc1.x + acc1.y;
        float s2 = acc2.x + acc2.y;
        float s3 = acc3.x + acc3.y;
        #pragma unroll
        for (int off = 1; off < 64; off <<= 1) {
            s0 += __shfl_xor(s0, off, 64);
            s1 += __shfl_xor(s1, off, 64);
            s2 += __shfl_xor(s2, off, 64);
            s3 += __shfl_xor(s3, off, 64);
        }

        // lane c owns gate c of unit m; gate 2 (update) is tanh = 2*sigmoid(2x)-1
        float a = s0;
        a = (l == 1) ? s1 : a;
        a = (l == 2) ? s2 : a;
        a = (l == 3) ? s3 : a;
        float ct = conv_lds[t];
        float x  = a + ct * w0 + bb;
        float xs = (l == 2) ? 2.0f * x : x;
        float y  = fast_sigmoid(xs);
        float g  = (l == 2) ? 2.0f * y - 1.0f : y;

        float f  = __shfl(g, 0, 64);
        float ii = __shfl(g, 1, 64);
        float gg = __shfl(g, 2, 64);
        float o  = __shfl(g, 3, 64);
        cx = f * cx + ii * gg;                            // identical on all lanes
        float th = 2.0f * fast_sigmoid(2.0f * cx) - 1.0f; // tanh(cx)
        float hx = o * th;

        if (l == 0) {
            // publish: value with tag ((t+2)&3)^2 embedded in the 2 LSBs
            u32 word = (__float_as_uint(hx) & ~3u) | (u32)(((t + 2) & 3) ^ 2);
            __hip_atomic_store(&tn[m], word, __ATOMIC_RELAXED, __HIP_MEMORY_SCOPE_AGENT);
            out[(size_t)t * HID + m] = hx;
            if (t == S_LEN - 1) {
                out[(size_t)S_LEN * HID + m]       = hx;   // final hx
                out[(size_t)S_LEN * HID + HID + m] = cx;   // final cx
            }
        }

        // ---- check the speculative sweep (loads have been hidden under FMA) ----
        if (t + 1 < S_LEN) {
            const u32 wn = (u32)(((t + 2) & 3) ^ 2);
            u32 c0 = (u32)qa, c1 = (u32)(qa >> 32);
            u32 c2 = (u32)qb, c3 = (u32)(qb >> 32);
            pend = 0xFu;
            if ((c0 & 3u) == wn) { v0 = c0; pend &= ~1u; }
            if ((c1 & 3u) == wn) { v1 = c1; pend &= ~2u; }
            if ((c2 & 3u) == wn) { v2 = c2; pend &= ~4u; }
            if ((c3 & 3u) == wn) { v3 = c3; pend &= ~8u; }
        }
    }
}

extern "C" void kernel_launch(void* const* d_in, const int* in_sizes, int n_in,
                              void* d_out, int out_size, void* d_ws, size_t ws_size,
                              hipStream_t stream) {
    const float* inp    = (const float*)d_in[0];
    const float* conv_w = (const float*)d_in[1];
    const float* conv_b = (const float*)d_in[2];
    const float* Wg     = (const float*)d_in[3];
    const float* bg     = (const float*)d_in[4];
    float* out = (float*)d_out;
    float* ws  = (float*)d_ws;

    // no memset needed: tag cycle {3,1}/{0,2} never aliases 0xAA poison (&3==2)
    void* args[] = {(void*)&inp, (void*)&conv_w, (void*)&conv_b,
                    (void*)&Wg, (void*)&bg, (void*)&out, (void*)&ws};
    hipLaunchCooperativeKernel((void*)qlstm_persistent,
                               dim3(NBLK), dim3(NTHR), args, 0, stream);
}

// Round 2
// 13455.679 us; speedup vs baseline: 2.0454x; 2.0454x over previous
//
#include <hip/hip_runtime.h>
#include <math.h>

#define S_LEN 4096
#define HID   2048
#define NBLK  256
#define NTHR  512   // 8 waves/block, 1 block/CU

typedef unsigned int       u32;
typedef unsigned long long u64;

// R6 = R4's proven skeleton (two barriers, wave-0 tail, coalesced publish) with:
//  - weights PINNED in registers: asm memory-clobber after init forbids the
//    compiler from sinking the 128 weight loads into the step loop (R4/R5 both
//    re-fetched weights every step: VGPR_Count 112/92 < 128 proves it).
//  - 4B tag-in-mantissa entries (tag = 2 mantissa LSBs, cycle {1,3}/{0,2};
//    0xAA poison &3==2 only aliases buf1's t=3 tag, overwritten at t=1).
//    Per-thread CONTIGUOUS 4-entry span -> 2 x u64 atomic polls per sweep
//    (half the MALL request rate of R4) + s_sleep(1) between failed sweeps.
//  - publish = single coalesced 32B store from the 8-lane tail (one request,
//    no R5-style partial-line write amplification).
//  - fast exp2-based sigmoid/tanh in the tail (validated in R5) + s_setprio(1)
//    so the publishing wave outranks the 7 spinning waves on its CU.

__device__ __forceinline__ float fast_sigmoid(float x) {
    float e = __builtin_amdgcn_exp2f(-1.44269504f * x);   // 2^(-x*log2e)
    return __builtin_amdgcn_rcpf(1.0f + e);
}

__global__ __launch_bounds__(NTHR, 2)
void qlstm_persistent(const float* __restrict__ inp,     // (S,1,4)
                      const float* __restrict__ conv_w,  // (4)
                      const float* __restrict__ conv_b,  // (1)
                      const float* __restrict__ Wg,      // (2049, 8192) row-major
                      const float* __restrict__ bg,      // (8192)
                      float* __restrict__ out,           // S*H + H + H
                      float* __restrict__ ws)            // scratch (poison 0xAA ok)
{
    const int b   = blockIdx.x;
    const int tid = threadIdx.x;
    const int l   = tid & 63;
    const int wv  = tid >> 6;

    u32* tb0 = (u32*)ws;            // [HID] tagged hx, parity 0 (holds even t)
    u32* tb1 = tb0 + HID + 16;      // [HID] tagged hx, parity 1 (line-padded)

    __shared__ __align__(16) float hx_lds[HID];
    __shared__ __align__(16) float conv_lds[S_LEN];
    __shared__ float gates_lds[32];
    __shared__ float colw0[32];
    __shared__ float colb[32];

    // ---------------- init phase ----------------
    {
        const float cw0 = conv_w[0], cw1 = conv_w[1], cw2 = conv_w[2], cw3 = conv_w[3];
        const float cb  = conv_b[0];
        for (int g = tid; g < S_LEN; g += NTHR) {
            float4 x = ((const float4*)inp)[g];
            float v = x.x*cw0 + x.y*cw1 + x.z*cw2 + x.w*cw3 + cb;
            conv_lds[g] = fast_sigmoid(v);
        }
    }
    // hx_0 = 0 lives purely in LDS: step 0 needs no global exchange at all.
    ((float4*)hx_lds)[tid] = make_float4(0.f, 0.f, 0.f, 0.f);

    // this wave's 4 global column indices (R4 mapping)
    int jcol[4];
    #pragma unroll
    for (int c = 0; c < 4; ++c) {
        int cgi  = 4*wv + c;
        int gate = cgi >> 3;
        int mi   = cgi & 7;
        jcol[c]  = (gate << 11) + (b * 8 + mi);     // gate*2048 + m
    }
    if (l == 0) {
        #pragma unroll
        for (int c = 0; c < 4; ++c) {
            int cgi = 4*wv + c;
            colw0[cgi] = Wg[jcol[c]];               // row 0 = input (c_t) weight
            colb[cgi]  = bg[jcol[c]];
        }
    }

    // persistent W registers: wreg[c][4j+r] = W[1 + 4l + 256j + r][jcol[c]]
    float wreg[4][32];
    #pragma unroll
    for (int j = 0; j < 8; ++j)
        #pragma unroll
        for (int r = 0; r < 4; ++r) {
            const float* rowp = Wg + (size_t)(1 + 4*l + 256*j + r) * 8192;
            #pragma unroll
            for (int c = 0; c < 4; ++c)
                wreg[c][4*j + r] = rowp[jcol[c]];
        }
    // forbid sinking the weight loads into the step loop: a potential store in
    // this asm makes moving any prior load past it illegal -> weights must be
    // materialized (in VGPRs) here, once.
    asm volatile("" ::: "memory");

    float cx = 0.0f;                    // live only in lanes tid<8
    const int m_out = b * 8 + tid;      // hidden index for tid<8
    const int e0 = tid * 4;             // this thread's contiguous 4-entry span

    u32 v0 = 0, v1 = 0, v2 = 0, v3 = 0;
    unsigned pend = 0;                  // t=0 needs nothing (hx_0 zeros pre-staged)

    // ---------------- recurrence ----------------
    for (int t = 0; t < S_LEN; ++t) {
        u32* tb = (t & 1) ? tb1 : tb0;  // hx_t lives here, tag ((t+1)&3)^2
        u32* tn = (t & 1) ? tb0 : tb1;  // hx_{t+1} goes here, tag ((t+2)&3)^2

        if (pend) {
            const u32 want = ((u32)(t + 1) & 3u) ^ 2u;
            int slept = 0;
            do {
                if (slept) __builtin_amdgcn_s_sleep(1);   // ~64cy backoff
                slept = 1;
                u64 qa = 0, qb = 0;
                if (pend & 3u)
                    qa = __hip_atomic_load((const u64*)(tb + e0),
                                           __ATOMIC_RELAXED, __HIP_MEMORY_SCOPE_AGENT);
                if (pend & 12u)
                    qb = __hip_atomic_load((const u64*)(tb + e0 + 2),
                                           __ATOMIC_RELAXED, __HIP_MEMORY_SCOPE_AGENT);
                u32 c0 = (u32)qa, c1 = (u32)(qa >> 32);
                u32 c2 = (u32)qb, c3 = (u32)(qb >> 32);
                if ((pend & 1u) && (c0 & 3u) == want) { v0 = c0; pend &= ~1u; }
                if ((pend & 2u) && (c1 & 3u) == want) { v1 = c1; pend &= ~2u; }
                if ((pend & 4u) && (c2 & 3u) == want) { v2 = c2; pend &= ~4u; }
                if ((pend & 8u) && (c3 & 3u) == want) { v3 = c3; pend &= ~8u; }
            } while (pend);
            uint4 st;
            st.x = v0 & ~3u; st.y = v1 & ~3u; st.z = v2 & ~3u; st.w = v3 & ~3u;
            ((uint4*)hx_lds)[tid] = st;     // ds_write_b128, conflict-free
        }
        __syncthreads();                    // A: hx_t staged

        // ---- 2048-MAC dot for this wave's 4 gate columns (R4-identical) ----
        const float4* hl = (const float4*)hx_lds;
        float acc0 = 0.f, acc1 = 0.f, acc2 = 0.f, acc3 = 0.f;
        #pragma unroll
        for (int j = 0; j < 8; ++j) {
            float4 h = hl[l + 64*j];        // ds_read_b128, conflict-free
            acc0 = fmaf(h.x, wreg[0][4*j+0], acc0);
            acc1 = fmaf(h.x, wreg[1][4*j+0], acc1);
            acc2 = fmaf(h.x, wreg[2][4*j+0], acc2);
            acc3 = fmaf(h.x, wreg[3][4*j+0], acc3);
            acc0 = fmaf(h.y, wreg[0][4*j+1], acc0);
            acc1 = fmaf(h.y, wreg[1][4*j+1], acc1);
            acc2 = fmaf(h.y, wreg[2][4*j+1], acc2);
            acc3 = fmaf(h.y, wreg[3][4*j+1], acc3);
            acc0 = fmaf(h.z, wreg[0][4*j+2], acc0);
            acc1 = fmaf(h.z, wreg[1][4*j+2], acc1);
            acc2 = fmaf(h.z, wreg[2][4*j+2], acc2);
            acc3 = fmaf(h.z, wreg[3][4*j+2], acc3);
            acc0 = fmaf(h.w, wreg[0][4*j+3], acc0);
            acc1 = fmaf(h.w, wreg[1][4*j+3], acc1);
            acc2 = fmaf(h.w, wreg[2][4*j+3], acc2);
            acc3 = fmaf(h.w, wreg[3][4*j+3], acc3);
        }
        #pragma unroll
        for (int off = 32; off; off >>= 1) {
            acc0 += __shfl_down(acc0, off, 64);
            acc1 += __shfl_down(acc1, off, 64);
            acc2 += __shfl_down(acc2, off, 64);
            acc3 += __shfl_down(acc3, off, 64);
        }
        if (l == 0) {
            gates_lds[4*wv + 0] = acc0;
            gates_lds[4*wv + 1] = acc1;
            gates_lds[4*wv + 2] = acc2;
            gates_lds[4*wv + 3] = acc3;
        }
        __syncthreads();                    // B: gates complete

        if (wv == 0) __builtin_amdgcn_s_setprio(1);   // publisher outranks spinners
        if (tid < 8) {
            float ct = conv_lds[t];
            float fg = gates_lds[tid]      + ct*colw0[tid]      + colb[tid];
            float ig = gates_lds[8 + tid]  + ct*colw0[8 + tid]  + colb[8 + tid];
            float gg = gates_lds[16 + tid] + ct*colw0[16 + tid] + colb[16 + tid];
            float og = gates_lds[24 + tid] + ct*colw0[24 + tid] + colb[24 + tid];
            float f  = fast_sigmoid(fg);
            float ii = fast_sigmoid(ig);
            float gv = 2.0f * fast_sigmoid(2.0f * gg) - 1.0f;   // tanh
            float o  = fast_sigmoid(og);
            cx = f * cx + ii * gv;
            float hx = o * (2.0f * fast_sigmoid(2.0f * cx) - 1.0f);
            // publish: value with tag ((t+2)&3)^2 in the 2 mantissa LSBs.
            // 8 lanes of wave 0 -> one coalesced 32B store (single request).
            u32 word = (__float_as_uint(hx) & ~3u) | (((u32)(t + 2) & 3u) ^ 2u);
            __hip_atomic_store(&tn[m_out], word,
                               __ATOMIC_RELAXED, __HIP_MEMORY_SCOPE_AGENT);
            out[(size_t)t * HID + m_out] = hx;
            if (t == S_LEN - 1) {
                out[(size_t)S_LEN * HID + m_out]       = hx;   // final hx
                out[(size_t)S_LEN * HID + HID + m_out] = cx;   // final cx
            }
        }
        if (wv == 0) __builtin_amdgcn_s_setprio(0);

        pend = 0xFu;
    }
}

extern "C" void kernel_launch(void* const* d_in, const int* in_sizes, int n_in,
                              void* d_out, int out_size, void* d_ws, size_t ws_size,
                              hipStream_t stream) {
    const float* inp    = (const float*)d_in[0];
    const float* conv_w = (const float*)d_in[1];
    const float* conv_b = (const float*)d_in[2];
    const float* Wg     = (const float*)d_in[3];
    const float* bg     = (const float*)d_in[4];
    float* out = (float*)d_out;
    float* ws  = (float*)d_ws;

    // no memset needed: tag cycle {1,3}/{0,2} — poison (&3==2) only aliases
    // buf1's t=3 tag, and every buf1 entry is overwritten at t=1 first.
    void* args[] = {(void*)&inp, (void*)&conv_w, (void*)&conv_b,
                    (void*)&Wg, (void*)&bg, (void*)&out, (void*)&ws};
    hipLaunchCooperativeKernel((void*)qlstm_persistent,
                               dim3(NBLK), dim3(NTHR), args, 0, stream);
}